// Round 8
// baseline (955.979 us; speedup 1.0000x reference)
//
#include <hip/hip_runtime.h>
#include <hip/hip_bf16.h>
#include <math.h>
#include <stdint.h>

// ---------- constants ----------
#define C_ 384
#define TOKENS 50176          // B*H*W = 16*56*56 = 16*64*49

typedef __bf16 bf16;
typedef __bf16 bf16x8 __attribute__((ext_vector_type(8)));
typedef __bf16 bf16x4 __attribute__((ext_vector_type(4)));
typedef float  f32x4  __attribute__((ext_vector_type(4)));

__device__ __forceinline__ float b2f(bf16 x) { return (float)x; }
__device__ __forceinline__ bf16  f2b(float x) { return (bf16)x; }

// tanh-form GELU: v * sigmoid(1.5957691 v + 0.0713548 v^3)
__device__ __forceinline__ float fast_gelu(float v) {
    float u2 = v * fmaf(v * v, 0.07135481f, 1.5957691f);
    return v / (1.0f + __expf(-u2));
}

// async global->LDS, 16 bytes per lane. LDS dest must be wave-uniform base + lane*16.
__device__ __forceinline__ void gld_lds16(const bf16* g, bf16* l) {
    __builtin_amdgcn_global_load_lds(
        (const __attribute__((address_space(1))) void*)g,
        (__attribute__((address_space(3))) void*)l, 16, 0, 0);
}

#define SB() __builtin_amdgcn_sched_barrier(0)
#define SYNC_FENCE() do { __builtin_amdgcn_sched_barrier(0); \
                          __builtin_amdgcn_s_barrier(); \
                          __builtin_amdgcn_sched_barrier(0); } while (0)
#define WAITVM(N) do { asm volatile("s_waitcnt vmcnt(" #N ")" ::: "memory"); SB(); } while (0)
#define WAITLG()  do { asm volatile("s_waitcnt lgkmcnt(0)" ::: "memory"); SB(); } while (0)

// ---------- K0: weight convert+transpose: in f32 [K][N] -> out bf16 [N][K] ----------
__global__ void wtrans_kernel(const float* __restrict__ in, bf16* __restrict__ out,
                              int K, int N) {
    int idx = blockIdx.x * 256 + threadIdx.x;
    if (idx >= K * N) return;
    int n = idx / K, k = idx % K;
    out[idx] = f2b(in[(size_t)k * N + n]);
}

// ---------- K1: LN1 + roll(-3,-3) + window partition. x BCHW f32 -> xw [50176][384] bf16 ----------
__global__ __launch_bounds__(256) void ln1_gather_kernel(
    const float* __restrict__ x, const float* __restrict__ g,
    const float* __restrict__ bt, bf16* __restrict__ xw) {
    int wave = threadIdx.x >> 6, lane = threadIdx.x & 63;
    int T = blockIdx.x * 4 + wave;
    int wi = T / 49, n = T % 49;
    int b = wi >> 6, w64 = wi & 63;
    int bh = w64 >> 3, bw = w64 & 7;
    int hs = bh * 7 + n / 7 + 3; if (hs >= 56) hs -= 56;
    int wsd = bw * 7 + n % 7 + 3; if (wsd >= 56) wsd -= 56;
    const float* xp = x + (size_t)b * C_ * 3136 + hs * 56 + wsd;
    float v[6];
    #pragma unroll
    for (int k = 0; k < 6; k++) v[k] = xp[(size_t)(lane + k * 64) * 3136];
    float s = v[0] + v[1] + v[2] + v[3] + v[4] + v[5];
    #pragma unroll
    for (int m = 32; m; m >>= 1) s += __shfl_xor(s, m);
    float mu = s * (1.0f / 384.0f);
    float s2 = 0.f;
    #pragma unroll
    for (int k = 0; k < 6; k++) { float d = v[k] - mu; s2 += d * d; }
    #pragma unroll
    for (int m = 32; m; m >>= 1) s2 += __shfl_xor(s2, m);
    float rstd = rsqrtf(s2 * (1.0f / 384.0f) + 1e-5f);
    bf16* op = xw + (size_t)T * 384;
    #pragma unroll
    for (int k = 0; k < 6; k++) {
        int c = lane + k * 64;
        op[c] = f2b((v[k] - mu) * rstd * g[c] + bt[c]);
    }
}

enum { EPI_NONE = 0, EPI_GELU = 1, EPI_PROJ = 2, EPI_FC2 = 3 };

// =============== BARRIER-FREE GEMM ===============
// C[M][N] = A[M][K] @ Wt[N][K]^T + bias. BM=256, BN=128, 8 waves (4M x 2N),
// 64x64/wave, BK=64 steps.
// BLDS=true (K==384): the ENTIRE 128x384 W-panel (96 KB) is staged to LDS once
// at block start (round-5-verified swizzle); ONE barrier total. K-loop has ZERO
// barriers: each wave self-paces {issue A(t+1) global->reg, 8 ds_read B(t),
// vmcnt(8)+lgkmcnt(0), 32 MFMA}. Waves slide independently.
// BLDS=false (fc2, K=1536): both operands global->reg (B is 1.2 MB, L2-hot);
// zero LDS, zero barriers; steady-state 16 loads in flight, WAITVM(16).
// A/B-fragment loads: per lane 16B at row*(K*2B): 16 rows x 64 B/instr (L1/L2
// served; row-7-verified path). vmcnt never drains mid-loop.

// two frags (kk=0 @+0B, kk=1 @+64B) from one per-lane row pointer
__device__ __forceinline__ void ldg2(f32x4& d0, f32x4& d1, const bf16* p) {
    asm volatile("global_load_dwordx4 %0, %2, off\n\t"
                 "global_load_dwordx4 %1, %2, off offset:64"
                 : "=&v"(d0), "=&v"(d1) : "v"(p) : "memory");
}

#define LDA(A0, A1)                                                     \
    do {                                                                \
        _Pragma("unroll")                                               \
        for (int i_ = 0; i_ < 4; i_++) ldg2(A0[i_], A1[i_], ga[i_]);    \
        _Pragma("unroll")                                               \
        for (int i_ = 0; i_ < 4; i_++) ga[i_] += 64;                    \
    } while (0)

#define LDB(B0, B1)                                                     \
    do {                                                                \
        _Pragma("unroll")                                               \
        for (int j_ = 0; j_ < 4; j_++) ldg2(B0[j_], B1[j_], gb[j_]);    \
        _Pragma("unroll")                                               \
        for (int j_ = 0; j_ < 4; j_++) gb[j_] += 64;                    \
    } while (0)

// BLDS: read b-frags for K-step TK from the resident W-panel.
// byte addr = row*768 + TK*128 + granule*16 ; granule=(kk*4+quad)^(lm&7)
#define RDBL(TK)                                                              \
    do {                                                                      \
        const char* wb_ = (const char*)Ws + (TK) * 128;                       \
        _Pragma("unroll")                                                     \
        for (int j_ = 0; j_ < 4; j_++)                                        \
            b0[j_] = *(const bf16x8*)(wb_ + bB + j_ * 12288);                 \
        _Pragma("unroll")                                                     \
        for (int j_ = 0; j_ < 4; j_++)                                        \
            b1[j_] = *(const bf16x8*)(wb_ + (bB ^ 64) + j_ * 12288);          \
    } while (0)

#define CVTB(BS0, BS1)                                                        \
    do {                                                                      \
        _Pragma("unroll")                                                     \
        for (int j_ = 0; j_ < 4; j_++) {                                      \
            b0[j_] = __builtin_bit_cast(bf16x8, BS0[j_]);                     \
            b1[j_] = __builtin_bit_cast(bf16x8, BS1[j_]);                     \
        }                                                                     \
    } while (0)

#define MMAC(A0, A1)                                                           \
    do {                                                                       \
        __builtin_amdgcn_s_setprio(1);                                         \
        _Pragma("unroll")                                                      \
        for (int j_ = 0; j_ < 4; j_++)                                         \
            _Pragma("unroll")                                                  \
            for (int i_ = 0; i_ < 4; i_++)                                     \
                acc[j_][i_] = __builtin_amdgcn_mfma_f32_16x16x32_bf16(         \
                    b0[j_], __builtin_bit_cast(bf16x8, A0[i_]), acc[j_][i_],   \
                    0, 0, 0);                                                  \
        _Pragma("unroll")                                                      \
        for (int j_ = 0; j_ < 4; j_++)                                         \
            _Pragma("unroll")                                                  \
            for (int i_ = 0; i_ < 4; i_++)                                     \
                acc[j_][i_] = __builtin_amdgcn_mfma_f32_16x16x32_bf16(         \
                    b1[j_], __builtin_bit_cast(bf16x8, A1[i_]), acc[j_][i_],   \
                    0, 0, 0);                                                  \
        __builtin_amdgcn_s_setprio(0);                                         \
        __builtin_amdgcn_sched_barrier(0);                                     \
    } while (0)

template <int EPI, bool BLDS>
__global__ __launch_bounds__(512, 2) void gemm_kernel(
    const bf16* __restrict__ A, const bf16* __restrict__ Wt,
    const float* __restrict__ bias, bf16* __restrict__ Cout,
    int Kdim, int Ndim,
    const float* __restrict__ resx,   // EPI_PROJ: x in BCHW f32
    const bf16* __restrict__ resb) {  // EPI_FC2 : x2 token-major bf16
    __shared__ __align__(16) bf16 Ws[BLDS ? 128 * 384 : 8];   // 96 KiB or none
    int t = threadIdx.x;

    // n-inner linear order + XCD-chunked bijective remap (m204)
    int nwg = gridDim.x * gridDim.y;
    int bid = blockIdx.y * gridDim.x + blockIdx.x;
    int q8 = nwg >> 3, r8 = nwg & 7, xcd = bid & 7, off = bid >> 3;
    int swz = (xcd < r8 ? xcd * (q8 + 1) : r8 * (q8 + 1) + (xcd - r8) * q8) + off;
    int n0 = (swz % gridDim.x) * 128;
    int m0 = (swz / gridDim.x) * 256;

    int lane = t & 63, wave = t >> 6;          // 8 waves
    int wr = wave >> 1, wc = wave & 1;         // 4M x 2N
    int quad = lane >> 4, lm = lane & 15;
    f32x4 acc[4][4] = {};   // acc[j][i]: C^T frag. n = quad*4+reg, m = lm

    if (BLDS) {
        // stage the whole 128 x 384 W-panel, swizzled source (round-5 verified)
        #pragma unroll
        for (int q = 0; q < 12; q++) {
            int idx = q * 512 + t;
            int row = idx / 48, cg = idx % 48;
            int sg = (cg & ~7) | ((cg & 7) ^ (row & 7));
            gld_lds16(Wt + (size_t)(n0 + row) * 384 + sg * 8, Ws + idx * 8);
        }
    }

    // per-lane fragment row pointers (advance 64 elems per K-step)
    const bf16* ga[4];
    #pragma unroll
    for (int i = 0; i < 4; i++)
        ga[i] = A + (size_t)(m0 + wr * 64 + i * 16 + lm) * Kdim + quad * 8;
    const bf16* gb[4];
    if (!BLDS) {
        #pragma unroll
        for (int j = 0; j < 4; j++)
            gb[j] = Wt + (size_t)(n0 + wc * 64 + j * 16 + lm) * Kdim + quad * 8;
    }
    int bB = (wc * 64 + lm) * 768 + (quad ^ (lm & 7)) * 16;   // BLDS read base

    f32x4 aE0[4], aE1[4], aO0[4], aO1[4];
    f32x4 bE0[4], bE1[4], bO0[4], bO1[4];   // !BLDS only
    bf16x8 b0[4], b1[4];

    int nt = Kdim >> 6;    // 6 (K=384) or 24 (K=1536): always even
    // ---- prologue ----
    LDA(aE0, aE1);                         // A(0)
    if (!BLDS) {
        LDB(bE0, bE1);                     // B(0); no barrier, no LDS at all
    } else {
        WAITVM(0);                         // W-panel + A(0) resident
        SYNC_FENCE();                      // the ONLY barrier in this kernel
    }

    for (int tk = 0; tk < nt; tk += 2) {
        // -------- even step tk --------
        if (BLDS) RDBL(tk);
        LDA(aO0, aO1);                     // A(tk+1)  (tk+1 <= nt-1: nt even)
        if (!BLDS) {
            LDB(bO0, bO1);                 // B(tk+1)
            WAITVM(16);                    // retire A(tk),B(tk); 16 in flight
            CVTB(bE0, bE1);
        } else {
            WAITVM(8);                     // retire A(tk); A(tk+1) in flight
            WAITLG();
        }
        MMAC(aE0, aE1);
        // -------- odd step tk+1 --------
        if (BLDS) RDBL(tk + 1);
        if (tk + 2 < nt) {
            LDA(aE0, aE1);                 // A(tk+2)
            if (!BLDS) {
                LDB(bE0, bE1);             // B(tk+2)
                WAITVM(16);                // retire A(tk+1),B(tk+1)
            } else {
                WAITVM(8);                 // retire A(tk+1)
            }
        } else {
            WAITVM(0);                     // drain tail
        }
        if (!BLDS) CVTB(bO0, bO1);
        else WAITLG();
        MMAC(aO0, aO1);
    }

    // ---- epilogue: m = m0+wr*64+i*16+lm ; n = n0+wc*64+j*16+quad*4+r
    #pragma unroll
    for (int i = 0; i < 4; i++) {
        int m = m0 + wr * 64 + i * 16 + lm;
        size_t resbase = 0;
        if (EPI == EPI_PROJ) {
            int wi = m / 49, n_ = m % 49;
            int b = wi >> 6, w64 = wi & 63;
            int bh = w64 >> 3, bw = w64 & 7;
            int hs = bh * 7 + n_ / 7 + 3; if (hs >= 56) hs -= 56;
            int wsd = bw * 7 + n_ % 7 + 3; if (wsd >= 56) wsd -= 56;
            resbase = (size_t)b * C_ * 3136 + hs * 56 + wsd;
        }
        #pragma unroll
        for (int j = 0; j < 4; j++) {
            int nb = n0 + wc * 64 + j * 16 + quad * 4;
            f32x4 bj = *(const f32x4*)(bias + nb);
            f32x4 v;
            #pragma unroll
            for (int r = 0; r < 4; r++) v[r] = acc[j][i][r] + bj[r];
            if (EPI == EPI_GELU) {
                #pragma unroll
                for (int r = 0; r < 4; r++) v[r] = fast_gelu(v[r]);
            }
            if (EPI == EPI_PROJ) {
                #pragma unroll
                for (int r = 0; r < 4; r++) v[r] += resx[resbase + (size_t)(nb + r) * 3136];
            }
            if (EPI == EPI_FC2) {
                bf16x4 rb = *(const bf16x4*)(resb + (size_t)m * 384 + nb);
                #pragma unroll
                for (int r = 0; r < 4; r++) v[r] += b2f(rb[r]);
            }
            bf16x4 o;
            #pragma unroll
            for (int r = 0; r < 4; r++) o[r] = f2b(v[r]);
            *(bf16x4*)(Cout + (size_t)m * Ndim + nb) = o;
        }
    }
}

// ---------- K3: MFMA windowed attention. one wave-block per (window, head) ----------
__global__ __launch_bounds__(64) void attn_mfma_kernel(const bf16* __restrict__ qkv,
                                                       bf16* __restrict__ aout) {
    __shared__ __align__(16) bf16 pbuf[64 * 72];
    __shared__ int reg_[64];
    int l = threadIdx.x;
    int wi = blockIdx.x / 12, h = blockIdx.x % 12;
    int i16 = l & 15, quad = l >> 4;

    {
        int tok = l < 49 ? l : 48;
        int w64 = wi & 63;
        int bh = w64 >> 3, bw = w64 & 7;
        int hh = bh * 7 + tok / 7, ww = bw * 7 + tok % 7;
        int fh = hh < 49 ? 0 : (hh < 53 ? 1 : 2);
        int fw = ww < 49 ? 0 : (ww < 53 ? 1 : 2);
        reg_[l] = fh * 3 + fw;
    }
    __syncthreads();

    const bf16* qbase = qkv + (size_t)wi * 49 * 1152 + h * 32;

    f32x4 s_[4][4] = {};
    bf16x8 af[4], bfr[4];
    #pragma unroll
    for (int mi = 0; mi < 4; mi++) {
        int m = mi * 16 + i16; if (m > 48) m = 48;
        af[mi] = *(const bf16x8*)(qbase + (size_t)m * 1152 + quad * 8);
    }
    #pragma unroll
    for (int nt = 0; nt < 4; nt++) {
        int n = nt * 16 + i16; if (n > 48) n = 48;
        bfr[nt] = *(const bf16x8*)(qbase + 384 + (size_t)n * 1152 + quad * 8);
    }
    #pragma unroll
    for (int mi = 0; mi < 4; mi++)
        #pragma unroll
        for (int nt = 0; nt < 4; nt++)
            s_[mi][nt] = __builtin_amdgcn_mfma_f32_16x16x32_bf16(af[mi], bfr[nt], s_[mi][nt], 0, 0, 0);

    int creg[4];
    #pragma unroll
    for (int nt = 0; nt < 4; nt++) {
        int c = nt * 16 + i16; if (c > 48) c = 48;
        creg[nt] = reg_[c];
    }

    const float scale = 0.17677669529663687f;
    #pragma unroll
    for (int mi = 0; mi < 4; mi++) {
        #pragma unroll
        for (int r = 0; r < 4; r++) {
            int row = mi * 16 + quad * 4 + r;
            int rreg = reg_[row];
            float v[4]; float mx = -1e30f;
            #pragma unroll
            for (int nt = 0; nt < 4; nt++) {
                int c = nt * 16 + i16;
                float x = s_[mi][nt][r] * scale;
                if (c > 48) x = -1e30f;
                else if (rreg != creg[nt]) x -= 100.0f;
                v[nt] = x; mx = fmaxf(mx, x);
            }
            #pragma unroll
            for (int m = 8; m; m >>= 1) mx = fmaxf(mx, __shfl_xor(mx, m));
            float sum = 0.f;
            #pragma unroll
            for (int nt = 0; nt < 4; nt++) { v[nt] = __expf(v[nt] - mx); sum += v[nt]; }
            #pragma unroll
            for (int m = 8; m; m >>= 1) sum += __shfl_xor(sum, m);
            float inv = 1.0f / sum;
            #pragma unroll
            for (int nt = 0; nt < 4; nt++)
                pbuf[row * 72 + nt * 16 + i16] = f2b(v[nt] * inv);
        }
    }
    __syncthreads();

    f32x4 o_[4][2] = {};
    const bf16* vbase = qkv + (size_t)wi * 49 * 1152 + 768 + h * 32;
    #pragma unroll
    for (int ks = 0; ks < 2; ks++) {
        bf16x8 pa[4];
        #pragma unroll
        for (int mi = 0; mi < 4; mi++)
            pa[mi] = *(const bf16x8*)(pbuf + (mi * 16 + i16) * 72 + ks * 32 + quad * 8);
        bf16x8 vb[2];
        #pragma unroll
        for (int nt = 0; nt < 2; nt++)
            #pragma unroll
            for (int j = 0; j < 8; j++) {
                int tok = ks * 32 + quad * 8 + j; if (tok > 48) tok = 48;
                vb[nt][j] = vbase[(size_t)tok * 1152 + nt * 16 + i16];
            }
        #pragma unroll
        for (int mi = 0; mi < 4; mi++)
            #pragma unroll
            for (int nt = 0; nt < 2; nt++)
                o_[mi][nt] = __builtin_amdgcn_mfma_f32_16x16x32_bf16(pa[mi], vb[nt], o_[mi][nt], 0, 0, 0);
    }

    bf16* obase = aout + (size_t)wi * 49 * 384 + h * 32;
    #pragma unroll
    for (int mi = 0; mi < 4; mi++)
        #pragma unroll
        for (int r = 0; r < 4; r++) {
            int row = mi * 16 + quad * 4 + r;
            if (row < 49) {
                #pragma unroll
                for (int nt = 0; nt < 2; nt++)
                    obase[(size_t)row * 384 + nt * 16 + i16] = f2b(o_[mi][nt][r]);
            }
        }
}

// ---------- K5: LN2 on token-major bf16 ----------
__global__ __launch_bounds__(256) void ln2_kernel(const bf16* __restrict__ x2,
                                                  const float* __restrict__ g,
                                                  const float* __restrict__ bt,
                                                  bf16* __restrict__ x2n) {
    int wave = threadIdx.x >> 6, lane = threadIdx.x & 63;
    int T = blockIdx.x * 4 + wave;
    const bf16* xp = x2 + (size_t)T * 384;
    float v[6];
    #pragma unroll
    for (int k = 0; k < 6; k++) v[k] = b2f(xp[lane + k * 64]);
    float s = v[0] + v[1] + v[2] + v[3] + v[4] + v[5];
    #pragma unroll
    for (int m = 32; m; m >>= 1) s += __shfl_xor(s, m);
    float mu = s * (1.0f / 384.0f);
    float s2 = 0.f;
    #pragma unroll
    for (int k = 0; k < 6; k++) { float d = v[k] - mu; s2 += d * d; }
    #pragma unroll
    for (int m = 32; m; m >>= 1) s2 += __shfl_xor(s2, m);
    float rstd = rsqrtf(s2 * (1.0f / 384.0f) + 1e-5f);
    bf16* op = x2n + (size_t)T * 384;
    #pragma unroll
    for (int k = 0; k < 6; k++) {
        int c = lane + k * 64;
        op[c] = f2b((v[k] - mu) * rstd * g[c] + bt[c]);
    }
}

// ---------- K8: window reverse + unshift + transpose to BCHW f32 ----------
__global__ __launch_bounds__(256) void untile_kernel(const bf16* __restrict__ otok,
                                                     float* __restrict__ out) {
    __shared__ float tile[56 * 65];
    int t = threadIdx.x;
    int b = blockIdx.x / 336;
    int rem = blockIdx.x % 336;
    int h = rem / 6;
    int c0 = (rem % 6) * 64;
    int hs = h + 53; if (hs >= 56) hs -= 56;
    int bh = hs / 7, th = hs % 7;
    #pragma unroll
    for (int pass = 0; pass < 14; pass++) {
        int w = pass * 4 + (t >> 6);
        int c = t & 63;
        int wsd = w + 53; if (wsd >= 56) wsd -= 56;
        int T = (b * 64 + bh * 8 + wsd / 7) * 49 + th * 7 + wsd % 7;
        tile[w * 65 + c] = b2f(otok[(size_t)T * 384 + c0 + c]);
    }
    __syncthreads();
    #pragma unroll
    for (int pass = 0; pass < 14; pass++) {
        int idx = pass * 256 + t;
        int c = idx / 56, w = idx % 56;
        out[((size_t)(b * 384 + c0 + c)) * 3136 + h * 56 + w] = tile[w * 65 + c];
    }
}

// ---------- launcher ----------
extern "C" void kernel_launch(void* const* d_in, const int* in_sizes, int n_in,
                              void* d_out, int out_size, void* d_ws, size_t ws_size,
                              hipStream_t stream) {
    (void)in_sizes; (void)n_in; (void)out_size; (void)ws_size;
    const float* x      = (const float*)d_in[0];
    const float* n1g    = (const float*)d_in[1];
    const float* n1b    = (const float*)d_in[2];
    const float* qkv_w  = (const float*)d_in[3];
    const float* qkv_b  = (const float*)d_in[4];
    const float* proj_w = (const float*)d_in[5];
    const float* proj_b = (const float*)d_in[6];
    const float* n2g    = (const float*)d_in[7];
    const float* n2b    = (const float*)d_in[8];
    const float* fc1_w  = (const float*)d_in[9];
    const float* fc1_b  = (const float*)d_in[10];
    const float* fc2_w  = (const float*)d_in[11];
    const float* fc2_b  = (const float*)d_in[12];
    float* out = (float*)d_out;
    char* ws = (char*)d_ws;

    bf16* qkv_wT = (bf16*)(ws + 0);          // 884736 B
    bf16* proj_wT = (bf16*)(ws + 884736);    // 294912 B
    bf16* fc1_wT = (bf16*)(ws + 1179648);    // 1179648 B
    bf16* fc2_wT = (bf16*)(ws + 2359296);    // 1179648 B
    bf16* xw   = (bf16*)(ws + 4194304);      // 38535168 B
    bf16* qkvb = (bf16*)(ws + 42729472);     // 115605504 B
    bf16* attn = (bf16*)(ws + 158334976);    // 38535168 B
    bf16* x2   = (bf16*)(ws + 4194304);      // alias xw (dead)
    bf16* x2n  = (bf16*)(ws + 42729472);     // alias qkv (dead)
    bf16* h1   = (bf16*)(ws + 81264640);     // 154140672 B (overlaps dead attn)
    bf16* otok = (bf16*)(ws + 235405312);    // 38535168 B  (peak ws = 274 MB)

    wtrans_kernel<<<(384 * 1152 + 255) / 256, 256, 0, stream>>>(qkv_w, qkv_wT, 384, 1152);
    wtrans_kernel<<<(384 * 384 + 255) / 256, 256, 0, stream>>>(proj_w, proj_wT, 384, 384);
    wtrans_kernel<<<(384 * 1536 + 255) / 256, 256, 0, stream>>>(fc1_w, fc1_wT, 384, 1536);
    wtrans_kernel<<<(1536 * 384 + 255) / 256, 256, 0, stream>>>(fc2_w, fc2_wT, 1536, 384);

    ln1_gather_kernel<<<TOKENS / 4, 256, 0, stream>>>(x, n1g, n1b, xw);

    // grids: x = n-blocks (BN=128), y = m-panels (BM=256, 196 panels)
    gemm_kernel<EPI_NONE, true><<<dim3(9, 196), 512, 0, stream>>>(
        xw, qkv_wT, qkv_b, qkvb, 384, 1152, nullptr, nullptr);

    attn_mfma_kernel<<<12288, 64, 0, stream>>>(qkvb, attn);

    gemm_kernel<EPI_PROJ, true><<<dim3(3, 196), 512, 0, stream>>>(
        attn, proj_wT, proj_b, x2, 384, 384, x, nullptr);

    ln2_kernel<<<TOKENS / 4, 256, 0, stream>>>(x2, n2g, n2b, x2n);

    gemm_kernel<EPI_GELU, true><<<dim3(12, 196), 512, 0, stream>>>(
        x2n, fc1_wT, fc1_b, h1, 384, 1536, nullptr, nullptr);

    // fc2: K=1536 (panel exceeds LDS) -> fully LDS-free, barrier-free variant
    gemm_kernel<EPI_FC2, false><<<dim3(3, 196), 512, 0, stream>>>(
        h1, fc2_wT, fc2_b, otok, 1536, 384, nullptr, x2);

    untile_kernel<<<16 * 336, 256, 0, stream>>>(otok, out);
}